// Round 1
// baseline (75649.725 us; speedup 1.0000x reference)
//
#include <hip/hip_runtime.h>
#include <math.h>

#define Tt  30
#define INP 32
#define HID 64
#define G4  256
#define NEG 0.2f

__device__ __forceinline__ float sigm(float v) { return 1.f / (1.f + expf(-v)); }

__device__ __forceinline__ void atomicMaxF(float* addr, float v) {
    if (v >= 0.f) atomicMax((int*)addr, __float_as_int(v));
    else          atomicMin((unsigned int*)addr, __float_as_uint(v));
}

// ---------------- LSTM layer 0: input (N,T,32), weights 32/64 x 256 ----------------
// block = 512 thr = 8 waves; 16 seqs/block; thread (sg=tid>>6, k=tid&63) owns seqs sg and sg+8, col k.
__global__ __launch_bounds__(512) void k_lstm0(
    const float* __restrict__ x, const float* __restrict__ Wih, const float* __restrict__ Whh,
    const float* __restrict__ bih, const float* __restrict__ bhh,
    float* __restrict__ hseq, float* __restrict__ hS, float* __restrict__ cS,
    int t0, int tc, int C, int N)
{
    __shared__ float4 sW[(INP + HID) * 64];   // gate-interleaved: [(j)*64+k] = {Wi,Wf,Wg,Wo}[j][k]  (96KB)
    __shared__ float4 sB[64];                 // combined bias per col (i,f,g,o)
    __shared__ float  sX[16][INP];
    __shared__ float  sH[16][HID];

    const int tid = threadIdx.x;
    const int k   = tid & 63;
    const int sg  = tid >> 6;             // 0..7
    const int n0  = blockIdx.x * 16;

    for (int idx = tid; idx < (INP + HID) * G4; idx += 512) {
        int j = idx >> 8, col = idx & 255;
        float v = (j < INP) ? Wih[j * G4 + col] : Whh[(j - INP) * G4 + col];
        int g = col >> 6, kk = col & 63;
        ((float*)sW)[(j * 64 + kk) * 4 + g] = v;
    }
    for (int idx = tid; idx < G4; idx += 512) {
        int g = idx >> 6, kk = idx & 63;
        ((float*)sB)[kk * 4 + g] = bih[idx] + bhh[idx];
    }

    float cA, cB;
    if (t0 == 0) {
        cA = cB = 0.f;
        sH[sg][k] = 0.f; sH[sg + 8][k] = 0.f;
    } else {
        cA = cS[(size_t)(n0 + sg) * HID + k];
        cB = cS[(size_t)(n0 + sg + 8) * HID + k];
        sH[sg][k]     = hS[(size_t)(n0 + sg) * HID + k];
        sH[sg + 8][k] = hS[(size_t)(n0 + sg + 8) * HID + k];
    }
    __syncthreads();

    for (int tt = 0; tt < tc; ++tt) {
        const int t = t0 + tt;
        { // stage x_t: 16*32 = 512 elements
            int s = tid >> 5, j = tid & 31;
            sX[s][j] = x[(size_t)(n0 + s) * Tt * INP + t * INP + j];
        }
        __syncthreads();

        float4 acc0 = sB[k], acc1 = sB[k];
        #pragma unroll
        for (int j = 0; j < INP; j += 4) {
            float4 xa = *(const float4*)&sX[sg][j];
            float4 xb = *(const float4*)&sX[sg + 8][j];
            #pragma unroll
            for (int u = 0; u < 4; ++u) {
                float4 w = sW[(j + u) * 64 + k];
                float fa = (&xa.x)[u], fb = (&xb.x)[u];
                acc0.x += w.x * fa; acc0.y += w.y * fa; acc0.z += w.z * fa; acc0.w += w.w * fa;
                acc1.x += w.x * fb; acc1.y += w.y * fb; acc1.z += w.z * fb; acc1.w += w.w * fb;
            }
        }
        #pragma unroll
        for (int j = 0; j < HID; j += 4) {
            float4 ha = *(const float4*)&sH[sg][j];
            float4 hb = *(const float4*)&sH[sg + 8][j];
            #pragma unroll
            for (int u = 0; u < 4; ++u) {
                float4 w = sW[(INP + j + u) * 64 + k];
                float fa = (&ha.x)[u], fb = (&hb.x)[u];
                acc0.x += w.x * fa; acc0.y += w.y * fa; acc0.z += w.z * fa; acc0.w += w.w * fa;
                acc1.x += w.x * fb; acc1.y += w.y * fb; acc1.z += w.z * fb; acc1.w += w.w * fb;
            }
        }

        float ia = sigm(acc0.x), fa = sigm(acc0.y), ga = tanhf(acc0.z), oa = sigm(acc0.w);
        cA = fa * cA + ia * ga; float hA = oa * tanhf(cA);
        float ib = sigm(acc1.x), fb = sigm(acc1.y), gb = tanhf(acc1.z), ob = sigm(acc1.w);
        cB = fb * cB + ib * gb; float hB = ob * tanhf(cB);

        __syncthreads();   // all reads of old sH/sX done
        sH[sg][k] = hA; sH[sg + 8][k] = hB;
        hseq[((size_t)(n0 + sg) * C + tt) * HID + k]     = hA;
        hseq[((size_t)(n0 + sg + 8) * C + tt) * HID + k] = hB;
        // next iteration's sX store + barrier publishes these before reads
    }

    if (t0 + tc < Tt) {
        cS[(size_t)(n0 + sg) * HID + k]     = cA;
        cS[(size_t)(n0 + sg + 8) * HID + k] = cB;
        hS[(size_t)(n0 + sg) * HID + k]     = sH[sg][k];
        hS[(size_t)(n0 + sg + 8) * HID + k] = sH[sg + 8][k];
    }
}

// ---------------- LSTM layer 1: input = layer0 h chunk (N,C,64) ----------------
__global__ __launch_bounds__(512) void k_lstm1(
    const float* __restrict__ hseq, const float* __restrict__ Wih, const float* __restrict__ Whh,
    const float* __restrict__ bih, const float* __restrict__ bhh,
    float* __restrict__ h1last, float* __restrict__ hS, float* __restrict__ cS,
    int t0, int tc, int C, int N)
{
    __shared__ float4 sW[(HID + HID) * 64];   // 128KB
    __shared__ float4 sB[64];
    __shared__ float  sX[16][HID];
    __shared__ float  sH[16][HID];

    const int tid = threadIdx.x;
    const int k   = tid & 63;
    const int sg  = tid >> 6;
    const int n0  = blockIdx.x * 16;

    for (int idx = tid; idx < (HID + HID) * G4; idx += 512) {
        int j = idx >> 8, col = idx & 255;
        float v = (j < HID) ? Wih[j * G4 + col] : Whh[(j - HID) * G4 + col];
        int g = col >> 6, kk = col & 63;
        ((float*)sW)[(j * 64 + kk) * 4 + g] = v;
    }
    for (int idx = tid; idx < G4; idx += 512) {
        int g = idx >> 6, kk = idx & 63;
        ((float*)sB)[kk * 4 + g] = bih[idx] + bhh[idx];
    }

    float cA, cB;
    if (t0 == 0) {
        cA = cB = 0.f;
        sH[sg][k] = 0.f; sH[sg + 8][k] = 0.f;
    } else {
        cA = cS[(size_t)(n0 + sg) * HID + k];
        cB = cS[(size_t)(n0 + sg + 8) * HID + k];
        sH[sg][k]     = hS[(size_t)(n0 + sg) * HID + k];
        sH[sg + 8][k] = hS[(size_t)(n0 + sg + 8) * HID + k];
    }
    __syncthreads();

    for (int tt = 0; tt < tc; ++tt) {
        const int t = t0 + tt;
        for (int idx = tid; idx < 16 * HID; idx += 512) {   // stage layer0 h_t
            int s = idx >> 6, j = idx & 63;
            sX[s][j] = hseq[((size_t)(n0 + s) * C + tt) * HID + j];
        }
        __syncthreads();

        float4 acc0 = sB[k], acc1 = sB[k];
        #pragma unroll
        for (int j = 0; j < HID; j += 4) {
            float4 xa = *(const float4*)&sX[sg][j];
            float4 xb = *(const float4*)&sX[sg + 8][j];
            #pragma unroll
            for (int u = 0; u < 4; ++u) {
                float4 w = sW[(j + u) * 64 + k];
                float fa = (&xa.x)[u], fb = (&xb.x)[u];
                acc0.x += w.x * fa; acc0.y += w.y * fa; acc0.z += w.z * fa; acc0.w += w.w * fa;
                acc1.x += w.x * fb; acc1.y += w.y * fb; acc1.z += w.z * fb; acc1.w += w.w * fb;
            }
        }
        #pragma unroll
        for (int j = 0; j < HID; j += 4) {
            float4 ha = *(const float4*)&sH[sg][j];
            float4 hb = *(const float4*)&sH[sg + 8][j];
            #pragma unroll
            for (int u = 0; u < 4; ++u) {
                float4 w = sW[(HID + j + u) * 64 + k];
                float fa = (&ha.x)[u], fb = (&hb.x)[u];
                acc0.x += w.x * fa; acc0.y += w.y * fa; acc0.z += w.z * fa; acc0.w += w.w * fa;
                acc1.x += w.x * fb; acc1.y += w.y * fb; acc1.z += w.z * fb; acc1.w += w.w * fb;
            }
        }

        float ia = sigm(acc0.x), fa = sigm(acc0.y), ga = tanhf(acc0.z), oa = sigm(acc0.w);
        cA = fa * cA + ia * ga; float hA = oa * tanhf(cA);
        float ib = sigm(acc1.x), fb = sigm(acc1.y), gb = tanhf(acc1.z), ob = sigm(acc1.w);
        cB = fb * cB + ib * gb; float hB = ob * tanhf(cB);

        __syncthreads();
        sH[sg][k] = hA; sH[sg + 8][k] = hB;
        if (t == Tt - 1) {
            h1last[(size_t)(n0 + sg) * HID + k]     = hA;
            h1last[(size_t)(n0 + sg + 8) * HID + k] = hB;
        }
    }

    if (t0 + tc < Tt) {
        cS[(size_t)(n0 + sg) * HID + k]     = cA;
        cS[(size_t)(n0 + sg + 8) * HID + k] = cB;
        hS[(size_t)(n0 + sg) * HID + k]     = sH[sg][k];
        hS[(size_t)(n0 + sg + 8) * HID + k] = sH[sg + 8][k];
    }
}

// ---------------- GAT1 projection: H1 = h @ W1 ; a_src/a_dst per head ----------------
__global__ __launch_bounds__(256) void k_gproj1(
    const float* __restrict__ hl, const float* __restrict__ W1,
    const float* __restrict__ as1, const float* __restrict__ ad1,
    float* __restrict__ H1, float* __restrict__ a_s, float* __restrict__ a_d)
{
    __shared__ float sh[64];
    const int n = blockIdx.x, tid = threadIdx.x;
    if (tid < 64) sh[tid] = hl[(size_t)n * 64 + tid];
    __syncthreads();
    float acc = 0.f;
    #pragma unroll
    for (int j = 0; j < 64; ++j) acc += sh[j] * W1[j * 256 + tid];
    H1[(size_t)n * 256 + tid] = acc;
    float ls = acc * as1[tid], ld = acc * ad1[tid];
    #pragma unroll
    for (int off = 32; off >= 1; off >>= 1) { ls += __shfl_down(ls, off); ld += __shfl_down(ld, off); }
    if ((tid & 63) == 0) { a_s[n * 4 + (tid >> 6)] = ls; a_d[n * 4 + (tid >> 6)] = ld; }
}

// ---------------- edge max (4 heads) ----------------
__global__ void k_emax1(const int* __restrict__ ei, const float* __restrict__ a_s,
                        const float* __restrict__ a_d, float* __restrict__ m, int E, int Et)
{
    int idx = blockIdx.x * blockDim.x + threadIdx.x;
    if (idx >= Et * 4) return;
    int e = idx >> 2, h = idx & 3;
    int s, d;
    if (e < E) { s = ei[e]; d = ei[E + e]; } else { s = d = e - E; }
    float a = a_s[s * 4 + h] + a_d[d * 4 + h];
    float l = a > 0.f ? a : NEG * a;
    atomicMaxF(&m[d * 4 + h], l);
}

// ---------------- edge scatter (4 heads x 64) ----------------
__global__ __launch_bounds__(256) void k_escat1(
    const int* __restrict__ ei, const float* __restrict__ a_s, const float* __restrict__ a_d,
    const float* __restrict__ m, float* __restrict__ ssum,
    const float* __restrict__ H1, float* __restrict__ un, int E, int Et)
{
    int e = blockIdx.x;
    int tid = threadIdx.x, h = tid >> 6;
    int s, d;
    if (e < E) { s = ei[e]; d = ei[E + e]; } else { s = d = e - E; }
    float a = a_s[s * 4 + h] + a_d[d * 4 + h];
    float l = a > 0.f ? a : NEG * a;
    float ev = expf(l - m[d * 4 + h]);
    if ((tid & 63) == 0) atomicAdd(&ssum[d * 4 + h], ev);
    atomicAdd(&un[(size_t)d * 256 + tid], ev * H1[(size_t)s * 256 + tid]);
}

// ---------------- GAT1 finalize: /sum + bias + relu (in place -> h2) ----------------
__global__ void k_efin1(float* __restrict__ un, const float* __restrict__ ssum,
                        const float* __restrict__ b1, int N)
{
    int idx = blockIdx.x * blockDim.x + threadIdx.x;
    if (idx >= N * 256) return;
    int n = idx >> 8, k = idx & 255, h = k >> 6;
    float v = un[idx] / ssum[n * 4 + h] + b1[k];
    un[idx] = v > 0.f ? v : 0.f;
}

// ---------------- GAT2 projection: H2 = h2 @ W2 ; scalar a2 ----------------
__global__ __launch_bounds__(256) void k_gproj2(
    const float* __restrict__ h2, const float* __restrict__ W2,
    const float* __restrict__ as2, const float* __restrict__ ad2,
    float* __restrict__ H2, float* __restrict__ a2s, float* __restrict__ a2d)
{
    __shared__ float sh2[4][256];
    const int tid = threadIdx.x;
    const int n0 = blockIdx.x * 4;
    for (int idx = tid; idx < 1024; idx += 256)
        sh2[idx >> 8][idx & 255] = h2[(size_t)(n0 + (idx >> 8)) * 256 + (idx & 255)];
    __syncthreads();
    int w = tid >> 6, L = tid & 63, c = L & 31, half = L >> 5;
    float acc = 0.f;
    #pragma unroll
    for (int j = 0; j < 128; ++j) acc += sh2[w][half * 128 + j] * W2[(half * 128 + j) * 32 + c];
    acc += __shfl_down(acc, 32);
    float ls = 0.f, ld = 0.f;
    if (L < 32) {
        H2[(size_t)(n0 + w) * 32 + c] = acc;
        ls = acc * as2[c]; ld = acc * ad2[c];
    }
    #pragma unroll
    for (int off = 16; off >= 1; off >>= 1) { ls += __shfl_down(ls, off); ld += __shfl_down(ld, off); }
    if (L == 0) { a2s[n0 + w] = ls; a2d[n0 + w] = ld; }
}

// ---------------- edge max (1 head) ----------------
__global__ void k_emax2(const int* __restrict__ ei, const float* __restrict__ a_s,
                        const float* __restrict__ a_d, float* __restrict__ m, int E, int Et)
{
    int e = blockIdx.x * blockDim.x + threadIdx.x;
    if (e >= Et) return;
    int s, d;
    if (e < E) { s = ei[e]; d = ei[E + e]; } else { s = d = e - E; }
    float a = a_s[s] + a_d[d];
    float l = a > 0.f ? a : NEG * a;
    atomicMaxF(&m[d], l);
}

// ---------------- edge scatter (32 cols) into d_out ----------------
__global__ __launch_bounds__(256) void k_escat2(
    const int* __restrict__ ei, const float* __restrict__ a_s, const float* __restrict__ a_d,
    const float* __restrict__ m, float* __restrict__ ssum,
    const float* __restrict__ H2, float* __restrict__ outp, int E, int Et)
{
    int idx = blockIdx.x * blockDim.x + threadIdx.x;
    if (idx >= Et * 32) return;
    int e = idx >> 5, c = idx & 31;
    int s, d;
    if (e < E) { s = ei[e]; d = ei[E + e]; } else { s = d = e - E; }
    float a = a_s[s] + a_d[d];
    float l = a > 0.f ? a : NEG * a;
    float ev = expf(l - m[d]);
    if (c == 0) atomicAdd(&ssum[d], ev);
    atomicAdd(&outp[(size_t)d * 32 + c], ev * H2[(size_t)s * 32 + c]);
}

// ---------------- GAT2 finalize ----------------
__global__ void k_efin2(float* __restrict__ outp, const float* __restrict__ ssum,
                        const float* __restrict__ b2, int N)
{
    int idx = blockIdx.x * blockDim.x + threadIdx.x;
    if (idx >= N * 32) return;
    outp[idx] = outp[idx] / ssum[idx >> 5] + b2[idx & 31];
}

__global__ void k_neginf(float* __restrict__ p, int n)
{
    int idx = blockIdx.x * blockDim.x + threadIdx.x;
    if (idx < n) p[idx] = -INFINITY;
}

static inline int cdiv(long long a, long long b) { return (int)((a + b - 1) / b); }

extern "C" void kernel_launch(void* const* d_in, const int* in_sizes, int n_in,
                              void* d_out, int out_size, void* d_ws, size_t ws_size,
                              hipStream_t stream)
{
    const float* x    = (const float*)d_in[0];
    const int*   ei   = (const int*)d_in[1];
    const float* Wih0 = (const float*)d_in[2];
    const float* Whh0 = (const float*)d_in[3];
    const float* bih0 = (const float*)d_in[4];
    const float* bhh0 = (const float*)d_in[5];
    const float* Wih1 = (const float*)d_in[6];
    const float* Whh1 = (const float*)d_in[7];
    const float* bih1 = (const float*)d_in[8];
    const float* bhh1 = (const float*)d_in[9];
    const float* W1   = (const float*)d_in[10];
    const float* as1  = (const float*)d_in[11];
    const float* ad1  = (const float*)d_in[12];
    const float* b1   = (const float*)d_in[13];
    const float* W2   = (const float*)d_in[14];
    const float* as2  = (const float*)d_in[15];
    const float* ad2  = (const float*)d_in[16];
    const float* b2   = (const float*)d_in[17];
    float* outp = (float*)d_out;

    const int N  = in_sizes[0] / (Tt * INP);
    const int E  = in_sizes[1] / 2;
    const int Et = E + N;

    float* ws = (float*)d_ws;
    const size_t N64 = (size_t)N * 64;

    float* h1last = ws;               // N*64, persists LSTM -> GAT
    float* rA = ws + N64;

    // region A (LSTM)
    float* h0s = rA;
    float* c0s = rA + N64;
    float* h1s = rA + 2 * N64;
    float* c1s = rA + 3 * N64;
    float* h0chunk = rA + 4 * N64;    // N*C*64

    long long availChunkRows = (long long)(ws_size / 4) - (long long)(5 * N64);
    int C = (int)(availChunkRows / (long long)N64);
    if (C > Tt) C = Tt;
    if (C < 1) C = 1;

    // region B (GAT) — overlays region A
    float* H1   = rA;                         // N*256
    float* un1  = H1 + (size_t)N * 256;       // N*256 (becomes h2)
    float* H2   = un1 + (size_t)N * 256;      // N*32
    float* as1p = H2 + (size_t)N * 32;        // N*4
    float* ad1p = as1p + (size_t)N * 4;
    float* m1   = ad1p + (size_t)N * 4;
    float* s1   = m1 + (size_t)N * 4;
    float* a2s  = s1 + (size_t)N * 4;         // N
    float* a2d  = a2s + N;
    float* m2   = a2d + N;
    float* s2   = m2 + N;

    // ---- LSTM (chunked over T) ----
    for (int t0 = 0; t0 < Tt; t0 += C) {
        int tc = Tt - t0 < C ? Tt - t0 : C;
        k_lstm0<<<dim3(N / 16), dim3(512), 0, stream>>>(x, Wih0, Whh0, bih0, bhh0,
                                                        h0chunk, h0s, c0s, t0, tc, C, N);
        k_lstm1<<<dim3(N / 16), dim3(512), 0, stream>>>(h0chunk, Wih1, Whh1, bih1, bhh1,
                                                        h1last, h1s, c1s, t0, tc, C, N);
    }

    // ---- init GAT accumulators (after LSTM: region B overlays region A) ----
    hipMemsetAsync(un1, 0, (size_t)N * 256 * 4, stream);
    hipMemsetAsync(s1, 0, (size_t)N * 4 * 4, stream);
    hipMemsetAsync(s2, 0, (size_t)N * 4, stream);
    hipMemsetAsync(outp, 0, (size_t)N * 32 * 4, stream);
    k_neginf<<<cdiv((long long)N * 4, 256), 256, 0, stream>>>(m1, N * 4);
    k_neginf<<<cdiv(N, 256), 256, 0, stream>>>(m2, N);

    // ---- GAT layer 1 ----
    k_gproj1<<<dim3(N), dim3(256), 0, stream>>>(h1last, W1, as1, ad1, H1, as1p, ad1p);
    k_emax1<<<cdiv((long long)Et * 4, 256), 256, 0, stream>>>(ei, as1p, ad1p, m1, E, Et);
    k_escat1<<<dim3(Et), dim3(256), 0, stream>>>(ei, as1p, ad1p, m1, s1, H1, un1, E, Et);
    k_efin1<<<cdiv((long long)N * 256, 256), 256, 0, stream>>>(un1, s1, b1, N);

    // ---- GAT layer 2 ----
    k_gproj2<<<dim3(N / 4), dim3(256), 0, stream>>>(un1, W2, as2, ad2, H2, a2s, a2d);
    k_emax2<<<cdiv(Et, 256), 256, 0, stream>>>(ei, a2s, a2d, m2, E, Et);
    k_escat2<<<cdiv((long long)Et * 32, 256), 256, 0, stream>>>(ei, a2s, a2d, m2, s2, H2, outp, E, Et);
    k_efin2<<<cdiv((long long)N * 32, 256), 256, 0, stream>>>(outp, s2, b2, N);
}